// Round 8
// baseline (240.756 us; speedup 1.0000x reference)
//
#include <hip/hip_runtime.h>

// Segmented CRF forward (OneCrfCCKSDecoder), exp-domain + MFMA, R8.
// T=128, B=512, E=128, EVENTLEN=8, NEG=-10000.
//
// R7 post-mortem: only 512 independent chains for 1024 SIMDs -> can't win by
// wave placement. R8 packs 16 batches into ONE wave via mfma_f32_16x16x32_f16:
//   D[m=j-tile][n=b] = sum_k A[m=j][k] * B[k][n=b],  A = exp(T) (128 regs,
//   8 j-tiles x 4 K-blocks), B = H (h vectors of 16 batches) from LDS.
// Layouts (verified guide mappings): A[m=lane&15][k=8*(lane>>4)+i],
// B[k=8*(lane>>4)+i][n=lane&15], D[m=4*(lane>>4)+reg (+16tau)][n=lane&15].
// Batches ride the n/col dimension so B and D agree lane-wise; the per-step
// "transpose" is an in-row k-regroup via one small LDS round trip:
// 8 ds_write_b64 -> 4 ds_read_b128, 16B chunks XOR-swizzled by (b&7) so both
// directions are <=2-way bank aliasing (free).
// 32 waves total (512/16), grid 32 x 64. Chain/step ~450-550cyc -> ~30us.
//
// Numerics = R6/R7-validated stale-renorm: scale 1/(16*max(u_stale)) folded
// into h at write time, M += log(c)+log16 bookkeeping exact; h f16-safe;
// E row 0 and te[127] exactly 0 (matches fp32 exp(-10000)=0).

typedef _Float16 f16x4 __attribute__((ext_vector_type(4)));
typedef _Float16 f16x8 __attribute__((ext_vector_type(8)));
typedef float    f32x4 __attribute__((ext_vector_type(4)));

#define NEG_VAL (-10000.0f)
#define LOG16   2.7725887222397812f

// LDS-ordering-only fence: wave-private buffer, does NOT drain vmcnt
// (feat prefetch stays in flight).
#define LDS_FENCE() asm volatile("s_waitcnt lgkmcnt(0)" ::: "memory")

__global__ __launch_bounds__(64, 1)
void crf_fwd(const float* __restrict__ feats,   // [128][512][128] f32
             const float* __restrict__ trans,   // [128][128] f32
             float* __restrict__ out)
{
    const int L    = threadIdx.x;      // 0..63
    const int bloc = L & 15;           // n-col role: batch-in-tile; m-row role for A
    const int q    = L >> 4;           // quad 0..3
    const int b7   = bloc & 7;
    const int b    = blockIdx.x * 16 + bloc;   // global batch (B/D role)

    // ---- A fragments: exp(T) tiles. A[m][k]: m=16*tau+bloc, k=32*kap+8*q+i
    f16x8 Afrag[8][4];
    #pragma unroll
    for (int tau = 0; tau < 8; ++tau) {
        const float* rowp = trans + (size_t)(16 * tau + bloc) * 128;
        #pragma unroll
        for (int kap = 0; kap < 4; ++kap) {
            const f32x4* p = (const f32x4*)(rowp + 32 * kap + 8 * q);
            f32x4 x = p[0], y = p[1];
            f16x8 f;
            f[0] = (_Float16)__expf(x[0]); f[1] = (_Float16)__expf(x[1]);
            f[2] = (_Float16)__expf(x[2]); f[3] = (_Float16)__expf(x[3]);
            f[4] = (_Float16)__expf(y[0]); f[5] = (_Float16)__expf(y[1]);
            f[6] = (_Float16)__expf(y[2]); f[7] = (_Float16)__expf(y[3]);
            Afrag[tau][kap] = f;
        }
    }
    // te in D layout: te[tau][r] = exp(trans[127][16*tau + 4*q + r])
    f32x4 te[8];
    #pragma unroll
    for (int tau = 0; tau < 8; ++tau) {
        f32x4 x = *(const f32x4*)(trans + 127 * 128 + 16 * tau + 4 * q);
        te[tau][0] = __expf(x[0]); te[tau][1] = __expf(x[1]);
        te[tau][2] = __expf(x[2]); te[tau][3] = __expf(x[3]);
    }

    // ---- LDS H buffer: 16 rows (b) x 128 f16 (k) = 4KB, 16B chunks
    // XOR-swizzled by b&7: chunk c of row b stored at chunk (c ^ b7).
    __shared__ __align__(16) char Hbuf[4096];
    int waddr[8], raddr[4];
    #pragma unroll
    for (int tau = 0; tau < 8; ++tau)   // write: k=16tau+4q+r -> chunk 2tau+(q>>1), half q&1
        waddr[tau] = bloc * 256 + 16 * ((2 * tau + (q >> 1)) ^ b7) + 8 * (q & 1);
    #pragma unroll
    for (int kap = 0; kap < 4; ++kap)   // read: k=32kap+8q.. -> chunk q+4kap
        raddr[kap] = bloc * 256 + 16 * ((q + 4 * kap) ^ b7);

    // ---- feat pipeline (D layout): feat[t][b][16tau+4q+r]
    const float* fb = feats + (size_t)b * 128 + 4 * q;
    f32x4 r1v[8], r2v[8], efi[8];
    #pragma unroll
    for (int tau = 0; tau < 8; ++tau) r1v[tau] = *(const f32x4*)(fb + 2 * 65536 + 16 * tau);
    #pragma unroll
    for (int tau = 0; tau < 8; ++tau) r2v[tau] = *(const f32x4*)(fb + 3 * 65536 + 16 * tau);
    #pragma unroll
    for (int tau = 0; tau < 8; ++tau) {   // efi for t=1: exp(feat[1]) * (1/16)
        f32x4 x = *(const f32x4*)(fb + 1 * 65536 + 16 * tau);
        efi[tau][0] = __expf(x[0]) * 0.0625f; efi[tau][1] = __expf(x[1]) * 0.0625f;
        efi[tau][2] = __expf(x[2]) * 0.0625f; efi[tau][3] = __expf(x[3]) * 0.0625f;
    }

    // ---- state
    f32x4 acc[8];                       // u[b][j], j = 16tau + 4q + r
    #pragma unroll
    for (int tau = 0; tau < 8; ++tau) { acc[tau][0]=1.f; acc[tau][1]=1.f; acc[tau][2]=1.f; acc[tau][3]=1.f; }
    float M        = (b == 0) ? 0.0f : NEG_VAL;  // init_fv zeroes only batch-0 row
    float alpha    = 0.0f;
    float inv_cur  = 0.0625f, logc_cur = LOG16;  // latest computed scale
    float logc_efi = LOG16;                      // log paired with current efi

    for (int t = 1; t < 128; ++t) {
        const bool upd = (t & 7) != 0;

        if (upd) {
            M += logc_efi;               // exact bookkeeping of scale in efi
            // publish h = u * exp(feat)*inv as f16 (R6-validated range)
            #pragma unroll
            for (int tau = 0; tau < 8; ++tau) {
                f16x4 hh;
                hh[0] = (_Float16)(acc[tau][0] * efi[tau][0]);
                hh[1] = (_Float16)(acc[tau][1] * efi[tau][1]);
                hh[2] = (_Float16)(acc[tau][2] * efi[tau][2]);
                hh[3] = (_Float16)(acc[tau][3] * efi[tau][3]);
                *(f16x4*)(Hbuf + waddr[tau]) = hh;
            }
            // shadow: in-lane part of next scale from current u
            f32x4 mm = acc[0];
            #pragma unroll
            for (int tau = 1; tau < 8; ++tau) {
                mm[0] = fmaxf(mm[0], acc[tau][0]); mm[1] = fmaxf(mm[1], acc[tau][1]);
                mm[2] = fmaxf(mm[2], acc[tau][2]); mm[3] = fmaxf(mm[3], acc[tau][3]);
            }
            float m = fmaxf(fmaxf(mm[0], mm[1]), fmaxf(mm[2], mm[3]));

            LDS_FENCE();                 // order writes -> reads (lgkm only)
            f16x8 Bf[4];
            #pragma unroll
            for (int kap = 0; kap < 4; ++kap)
                Bf[kap] = *(const f16x8*)(Hbuf + raddr[kap]);

            // cross-lane part of max (overlaps read latency / MFMA issue)
            m = fmaxf(m, __shfl_xor(m, 16, 64));
            m = fmaxf(m, __shfl_xor(m, 32, 64));

            // ---- 8 j-tiles x 4 K-blocks of MFMA: acc = E . H ----
            #pragma unroll
            for (int tau = 0; tau < 8; ++tau) {
                f32x4 d = {0.f, 0.f, 0.f, 0.f};
                d = __builtin_amdgcn_mfma_f32_16x16x32_f16(Afrag[tau][0], Bf[0], d, 0, 0, 0);
                d = __builtin_amdgcn_mfma_f32_16x16x32_f16(Afrag[tau][1], Bf[1], d, 0, 0, 0);
                d = __builtin_amdgcn_mfma_f32_16x16x32_f16(Afrag[tau][2], Bf[2], d, 0, 0, 0);
                d = __builtin_amdgcn_mfma_f32_16x16x32_f16(Afrag[tau][3], Bf[3], d, 0, 0, 0);
                acc[tau] = d;
            }
            inv_cur  = __builtin_amdgcn_rcpf(m) * 0.0625f;
            logc_cur = __logf(m) + LOG16;
        } else {
            // ---- event boundary: alpha += M + log(sum_j u[b][j]*te[j]) ----
            float s0 = 0.f, s1 = 0.f, s2 = 0.f, s3 = 0.f;
            #pragma unroll
            for (int tau = 0; tau < 8; ++tau) {
                s0 = fmaf(acc[tau][0], te[tau][0], s0);
                s1 = fmaf(acc[tau][1], te[tau][1], s1);
                s2 = fmaf(acc[tau][2], te[tau][2], s2);
                s3 = fmaf(acc[tau][3], te[tau][3], s3);
            }
            float s = (s0 + s1) + (s2 + s3);
            s += __shfl_xor(s, 16, 64);
            s += __shfl_xor(s, 32, 64);
            alpha += M + __logf(s);
        }

        // rotate feat pipeline; build efi for t+1 with latest scale
        if (t + 1 < 128) {
            #pragma unroll
            for (int tau = 0; tau < 8; ++tau) {
                f32x4 x = r1v[tau];
                efi[tau][0] = __expf(x[0]) * inv_cur; efi[tau][1] = __expf(x[1]) * inv_cur;
                efi[tau][2] = __expf(x[2]) * inv_cur; efi[tau][3] = __expf(x[3]) * inv_cur;
            }
            logc_efi = logc_cur;
            #pragma unroll
            for (int tau = 0; tau < 8; ++tau) r1v[tau] = r2v[tau];
            if (t + 3 < 128) {
                #pragma unroll
                for (int tau = 0; tau < 8; ++tau)
                    r2v[tau] = *(const f32x4*)(fb + (size_t)(t + 3) * 65536 + 16 * tau);
            }
        }
    }

    // ---- terminal accumulation ----
    {
        float s0 = 0.f, s1 = 0.f, s2 = 0.f, s3 = 0.f;
        #pragma unroll
        for (int tau = 0; tau < 8; ++tau) {
            s0 = fmaf(acc[tau][0], te[tau][0], s0);
            s1 = fmaf(acc[tau][1], te[tau][1], s1);
            s2 = fmaf(acc[tau][2], te[tau][2], s2);
            s3 = fmaf(acc[tau][3], te[tau][3], s3);
        }
        float s = (s0 + s1) + (s2 + s3);
        s += __shfl_xor(s, 16, 64);
        s += __shfl_xor(s, 32, 64);
        alpha += M + __logf(s);
    }

    // per-batch alpha lives (replicated over q) at lanes with q==0
    float v = (q == 0) ? alpha : 0.0f;
    #pragma unroll
    for (int off = 1; off < 64; off <<= 1)
        v += __shfl_xor(v, off, 64);
    if (L == 0)
        atomicAdd(out, v * (1.0f / (512.0f * 16.0f)));
}

extern "C" void kernel_launch(void* const* d_in, const int* in_sizes, int n_in,
                              void* d_out, int out_size, void* d_ws, size_t ws_size,
                              hipStream_t stream) {
    const float* feats = (const float*)d_in[0];   // [128,512,128] f32
    const float* trans = (const float*)d_in[1];   // [128,128] f32
    float* out = (float*)d_out;                   // scalar f32

    hipMemsetAsync(out, 0, sizeof(float), stream);
    crf_fwd<<<32, 64, 0, stream>>>(feats, trans, out);
}

// Round 9
// 113.226 us; speedup vs baseline: 2.1263x; 2.1263x over previous
//
#include <hip/hip_runtime.h>

// Segmented CRF forward (OneCrfCCKSDecoder), exp-domain + MFMA, R9.
// T=128, B=512, E=128, EVENTLEN=8, NEG=-10000.
//
// R8 post-mortem: correct but one wave carried the whole 128-j update
// (32 MFMA + 32 expf/step, 32 waves chip-wide, nothing to hide latency).
// R9: 32 wgs x 512 thr (8 waves). Wave w owns j-tile tau=w: 4 MFMAs/step
// (2 independent 2-chains). Waves couple ONLY through the H buffer in LDS:
//   write own k-slice (1 ds_write_b64/lane) -> lgkmcnt+s_barrier ->
//   read full H (4 ds_read_b128, XOR-swizzled, contiguous-equivalent banks).
// MFMA layouts identical to R8 (absmax 0.0 validated):
//   A[m=lane&15][k=32kap+8q+i], B[k=32kap+8q+i][n=lane&15],
//   D[m=4q+r][n=lane&15], m/j-tile = 16w+..., n = batch.
//
// Renorm: fixed per-step scale e^-6 folded into h (M += 6 exact bookkeeping),
// plus EXACT per-batch max-renorm at every event boundary (every 8 steps),
// piggybacked on the alpha partial exchange (Spart/Mpart in LDS). Drift over
// <=7 steps is small => h stays ~<= e^8 << f16 max e^11.1; u f32-safe.
// E row 0 and te[127] are exactly 0 (matches fp32 exp(-10000)=0).

typedef _Float16 f16x4 __attribute__((ext_vector_type(4)));
typedef _Float16 f16x8 __attribute__((ext_vector_type(8)));
typedef float    f32x4 __attribute__((ext_vector_type(4)));

#define NEG_VAL   (-10000.0f)
#define C_SCALE   0.0024787521766663585f   // e^-6
#define LOG_C     6.0f

// order own LDS writes + join workgroup; does NOT drain vmcnt (feat
// prefetch loads stay in flight across the barrier)
#define LDS_BARRIER() asm volatile("s_waitcnt lgkmcnt(0)\n\ts_barrier" ::: "memory")

__global__ __launch_bounds__(512)
void crf_fwd(const float* __restrict__ feats,   // [128][512][128] f32
             const float* __restrict__ trans,   // [128][128] f32
             float* __restrict__ out)
{
    const int tid  = threadIdx.x;
    const int w    = tid >> 6;         // wave id 0..7 = j-tile tau
    const int lane = tid & 63;
    const int bloc = lane & 15;        // batch-in-tile (n role; m role for A)
    const int q    = lane >> 4;        // quad 0..3
    const int b    = blockIdx.x * 16 + bloc;   // global batch

    // ---- A fragments: exp(T) rows j = 16w + bloc, k = 32kap + 8q + i ----
    f16x8 Afrag[4];
    {
        const float* rowp = trans + (size_t)(16 * w + bloc) * 128;
        #pragma unroll
        for (int kap = 0; kap < 4; ++kap) {
            const f32x4* p = (const f32x4*)(rowp + 32 * kap + 8 * q);
            f32x4 x = p[0], y = p[1];
            f16x8 f;
            f[0] = (_Float16)__expf(x[0]); f[1] = (_Float16)__expf(x[1]);
            f[2] = (_Float16)__expf(x[2]); f[3] = (_Float16)__expf(x[3]);
            f[4] = (_Float16)__expf(y[0]); f[5] = (_Float16)__expf(y[1]);
            f[6] = (_Float16)__expf(y[2]); f[7] = (_Float16)__expf(y[3]);
            Afrag[kap] = f;
        }
    }
    // te in D layout for own tile: te[r] = exp(trans[127][16w + 4q + r])
    f32x4 te;
    {
        f32x4 x = *(const f32x4*)(trans + 127 * 128 + 16 * w + 4 * q);
        te[0] = __expf(x[0]); te[1] = __expf(x[1]);
        te[2] = __expf(x[2]); te[3] = __expf(x[3]);
    }

    // ---- LDS: H (16 batches x 128 k f16, 16B chunks XOR-swizzled by bloc),
    //           Spart/Mpart ([bloc][w]) for boundary exchange ----
    __shared__ __align__(16) char  Hbuf[4096];
    __shared__ float Spart[16 * 8];
    __shared__ float Mpart[16 * 8];

    const int waddr = bloc * 256 + (((2 * w + (q >> 1)) ^ bloc) * 16) + 8 * (q & 1);
    int raddr[4];
    #pragma unroll
    for (int kap = 0; kap < 4; ++kap)
        raddr[kap] = bloc * 256 + (((4 * kap + q) ^ bloc) * 16);

    // ---- feat pipeline: lane needs feat[t][b][16w + 4q + r] (one f32x4) ----
    const float* fb = feats + (size_t)b * 128 + 16 * w + 4 * q;
    f32x4 efi;   // exp(feat[t]) * scale, for the NEXT update's h
    f32x4 r1v, r2v;
    {
        f32x4 x = *(const f32x4*)(fb + 1 * 65536);
        efi[0] = __expf(x[0]) * C_SCALE; efi[1] = __expf(x[1]) * C_SCALE;
        efi[2] = __expf(x[2]) * C_SCALE; efi[3] = __expf(x[3]) * C_SCALE;
        r1v = *(const f32x4*)(fb + 2 * 65536);
        r2v = *(const f32x4*)(fb + 3 * 65536);
    }
    float logc_cur = LOG_C;            // log of scale baked into current efi

    f32x4 acc = {1.f, 1.f, 1.f, 1.f};  // u[b][j], j = 16w + 4q + r
    float M     = (b == 0) ? 0.0f : NEG_VAL;  // init_fv zeroes only batch-0 row
    float alpha = 0.0f;

    #pragma unroll 8
    for (int t = 1; t < 128; ++t) {
        const bool upd = (t & 7) != 0;
        float sc_next = C_SCALE;       // scale for t+1's efi (boundary overrides)
        float lg_next = LOG_C;

        if (upd) {
            // ---- publish h = u * efi (scale inside efi; M bookkeeping) ----
            M += logc_cur;
            f16x4 hh;
            hh[0] = (_Float16)(acc[0] * efi[0]);
            hh[1] = (_Float16)(acc[1] * efi[1]);
            hh[2] = (_Float16)(acc[2] * efi[2]);
            hh[3] = (_Float16)(acc[3] * efi[3]);
            *(f16x4*)(Hbuf + waddr) = hh;
            LDS_BARRIER();

            f16x8 B0 = *(const f16x8*)(Hbuf + raddr[0]);
            f16x8 B1 = *(const f16x8*)(Hbuf + raddr[1]);
            f16x8 B2 = *(const f16x8*)(Hbuf + raddr[2]);
            f16x8 B3 = *(const f16x8*)(Hbuf + raddr[3]);

            // ---- 4 MFMAs, two independent chains ----
            f32x4 z = {0.f, 0.f, 0.f, 0.f};
            f32x4 da = __builtin_amdgcn_mfma_f32_16x16x32_f16(Afrag[0], B0, z, 0, 0, 0);
            f32x4 db = __builtin_amdgcn_mfma_f32_16x16x32_f16(Afrag[1], B1, z, 0, 0, 0);
            da = __builtin_amdgcn_mfma_f32_16x16x32_f16(Afrag[2], B2, da, 0, 0, 0);
            db = __builtin_amdgcn_mfma_f32_16x16x32_f16(Afrag[3], B3, db, 0, 0, 0);
            acc = da + db;
        } else {
            // ---- boundary: per-wave partials (sum for alpha, max for renorm)
            float s = acc[0] * te[0] + acc[1] * te[1]
                    + acc[2] * te[2] + acc[3] * te[3];
            float m = fmaxf(fmaxf(acc[0], acc[1]), fmaxf(acc[2], acc[3]));
            s += __shfl_xor(s, 16, 64);
            s += __shfl_xor(s, 32, 64);
            m = fmaxf(m, __shfl_xor(m, 16, 64));
            m = fmaxf(m, __shfl_xor(m, 32, 64));
            if (q == 0) {
                Spart[bloc * 8 + w] = s;
                Mpart[bloc * 8 + w] = m;
            }
            LDS_BARRIER();

            f32x4 sa = *(const f32x4*)&Spart[bloc * 8];
            f32x4 sb = *(const f32x4*)&Spart[bloc * 8 + 4];
            f32x4 ma = *(const f32x4*)&Mpart[bloc * 8];
            f32x4 mb = *(const f32x4*)&Mpart[bloc * 8 + 4];
            float r = ((sa[0] + sa[1]) + (sa[2] + sa[3]))
                    + ((sb[0] + sb[1]) + (sb[2] + sb[3]));
            float cmax = fmaxf(fmaxf(fmaxf(ma[0], ma[1]), fmaxf(ma[2], ma[3])),
                               fmaxf(fmaxf(mb[0], mb[1]), fmaxf(mb[2], mb[3])));

            alpha += M + __logf(r);    // per-batch, replicated over q & waves
            // exact renorm folded into the NEXT update's scale
            sc_next = C_SCALE * __builtin_amdgcn_rcpf(cmax);
            lg_next = LOG_C + __logf(cmax);
        }

        // ---- rotate feat pipeline; build efi for t+1 with chosen scale ----
        if (t + 1 < 128) {
            efi[0] = __expf(r1v[0]) * sc_next; efi[1] = __expf(r1v[1]) * sc_next;
            efi[2] = __expf(r1v[2]) * sc_next; efi[3] = __expf(r1v[3]) * sc_next;
            logc_cur = lg_next;
            r1v = r2v;
            if (t + 3 < 128) r2v = *(const f32x4*)(fb + (size_t)(t + 3) * 65536);
        }
    }

    // ---- terminal accumulation (sum exchange only) ----
    {
        float s = acc[0] * te[0] + acc[1] * te[1]
                + acc[2] * te[2] + acc[3] * te[3];
        s += __shfl_xor(s, 16, 64);
        s += __shfl_xor(s, 32, 64);
        if (q == 0) Spart[bloc * 8 + w] = s;
        LDS_BARRIER();
        f32x4 sa = *(const f32x4*)&Spart[bloc * 8];
        f32x4 sb = *(const f32x4*)&Spart[bloc * 8 + 4];
        float r = ((sa[0] + sa[1]) + (sa[2] + sa[3]))
                + ((sb[0] + sb[1]) + (sb[2] + sb[3]));
        alpha += M + __logf(r);
    }

    // alpha is replicated across q and waves; reduce in wave 0.
    if (w == 0) {
        float v = alpha;               // 64 lanes = 4x replication of 16 batches
        #pragma unroll
        for (int off = 1; off < 64; off <<= 1)
            v += __shfl_xor(v, off, 64);
        if (lane == 0)
            atomicAdd(out, v * (1.0f / (4.0f * 512.0f * 16.0f)));
    }
}

extern "C" void kernel_launch(void* const* d_in, const int* in_sizes, int n_in,
                              void* d_out, int out_size, void* d_ws, size_t ws_size,
                              hipStream_t stream) {
    const float* feats = (const float*)d_in[0];   // [128,512,128] f32
    const float* trans = (const float*)d_in[1];   // [128,128] f32
    float* out = (float*)d_out;                   // scalar f32

    hipMemsetAsync(out, 0, sizeof(float), stream);
    crf_fwd<<<32, 512, 0, stream>>>(feats, trans, out);
}